// Round 4
// baseline (701.912 us; speedup 1.0000x reference)
//
#include <hip/hip_runtime.h>

#define DIM    192
#define HEADS  6
#define NTOK   49
#define NWIN   64

typedef __attribute__((ext_vector_type(8))) short short8;
typedef __attribute__((ext_vector_type(4))) float f32x4;

// LDS strides (elements). All bf16 row strides give 16B-aligned ds_read_b128
// (stride*2 % 16 == 0) and bank stride 4 (2-way conflict = free per m136).
#define XS 200   // sx / sq / kstage row stride (bf16), 192 cols + pad
#define VS 72    // sv (V^T) row stride (bf16), 64 tokens + pad
#define SS 65    // S row stride (fp32)
#define PS 72    // P row stride (bf16)

#define BIAS_ELEMS (HEADS * NTOK * NTOK)             // 14406 floats
#define WQKV_SOFF   28864                            // ushort offset in ws (57728 B)
#define WQKV_ELEMS  (3 * DIM * DIM)                  // 110592
#define WPROJ_SOFF  (WQKV_SOFF + WQKV_ELEMS)         // 139456
#define WPROJ_ELEMS (DIM * DIM)                      // 36864
#define CMB_BOFF    ((size_t)(WPROJ_SOFF + WPROJ_ELEMS) * 2)   // byte offset of cmb in ws
#define CMB_ELEMS   (NWIN * HEADS * NTOK * NTOK)     // 921984 floats (3.69 MB)

__device__ __forceinline__ unsigned short f2bf(float f) {
    unsigned int u = __float_as_uint(f);
    u += 0x7FFFu + ((u >> 16) & 1u);   // round-to-nearest-even
    return (unsigned short)(u >> 16);
}

// ---------------- K1: bias gather + bf16 weight conversion (+ cmb table) ----------------
__global__ void wa_prep_kernel(const int* __restrict__ rpi,
                               const float* __restrict__ rpb,
                               const float* __restrict__ qkv_w,
                               const float* __restrict__ proj_w,
                               const float* __restrict__ maskp,
                               float* __restrict__ bias,
                               unsigned short* __restrict__ wqkv,
                               unsigned short* __restrict__ wproj,
                               float* __restrict__ cmb) {
    __shared__ int is64_s;
    if (threadIdx.x < 64) {
        int z = (rpi[2 * (int)threadIdx.x + 1] == 0) ? 1 : 0;
        unsigned long long b = __ballot(z);
        if (threadIdx.x == 0) is64_s = (__popcll(b) >= 48) ? 1 : 0;
    }
    __syncthreads();
    const int is64 = is64_s;
    const int base3 = BIAS_ELEMS + WQKV_ELEMS + WPROJ_ELEMS;
    const int total = base3 + (cmb ? CMB_ELEMS : 0);
    for (int idx = blockIdx.x * blockDim.x + threadIdx.x; idx < total;
         idx += gridDim.x * blockDim.x) {
        if (idx < BIAS_ELEMS) {
            int h  = idx / (NTOK * NTOK);
            int nm = idx - h * (NTOK * NTOK);
            int r  = is64 ? rpi[2 * nm] : rpi[nm];
            bias[idx] = rpb[r * HEADS + h];
        } else if (idx < BIAS_ELEMS + WQKV_ELEMS) {
            int i = idx - BIAS_ELEMS;
            wqkv[i] = f2bf(qkv_w[i]);
        } else if (idx < base3) {
            int i = idx - BIAS_ELEMS - WQKV_ELEMS;
            wproj[i] = f2bf(proj_w[i]);
        } else {
            // cmb[win][h][i*49+j] = rpb[rpi[i*49+j]][h] + mask[win][i*49+j]
            int i2  = idx - base3;
            int win = i2 / (HEADS * NTOK * NTOK);
            int rem = i2 - win * (HEADS * NTOK * NTOK);
            int h   = rem / (NTOK * NTOK);
            int nm  = rem - h * (NTOK * NTOK);
            int r   = is64 ? rpi[2 * nm] : rpi[nm];
            cmb[i2] = rpb[r * HEADS + h] + maskp[win * (NTOK * NTOK) + nm];
        }
    }
}

// ---------------- K2: fused QKV + attention + output projection ----------------
// One block per window, 2 blocks/CU (LDS 79360 B <= 80 KiB).
// __launch_bounds__(512, 2): hipcc treats the 2nd arg CUDA-style (min blocks/CU)
// — round-2 evidence: (512,4) produced a 64-VGPR cap (=8 waves/SIMD budget) and
// spilled phase-1 acc to scratch (+156 MB HBM). (512,2) caps at 128 VGPR which
// fits the ~104-reg natural demand with zero spill while keeping 2 blocks/CU.
// K lives in REGISTERS during the head loop (48 VGPR/lane). The union region
// uSP serves three lives: sx (staged x) -> kstage (K) -> S (fp32) + P (bf16).
// After head h, sq cols [32h,32h+32) hold the attention output (Q dead), and
// phase 3 runs the output projection in-block against L2-resident wproj.
template <bool CMB>
__global__ __launch_bounds__(512, 2)
void wa_attn_kernel(const float* __restrict__ x,
                    const float* __restrict__ maskp,
                    const unsigned short* __restrict__ wqkv,
                    const float* __restrict__ qkv_b,
                    const float* __restrict__ biasp,
                    const unsigned short* __restrict__ wproj,
                    const float* __restrict__ proj_b,
                    const float* __restrict__ cmbp,
                    float* __restrict__ out) {
    __shared__ __attribute__((aligned(16))) float uSP[64 * SS + 64 * (PS / 2)]; // 25856 B
    __shared__ __attribute__((aligned(16))) unsigned short sq[64 * XS];   // 25600 B
    __shared__ __attribute__((aligned(16))) unsigned short sv[DIM * VS];  // 27648 B (V^T)
    __shared__ float sinv[64];

    unsigned short* sx     = (unsigned short*)uSP;
    unsigned short* kstage = (unsigned short*)uSP;
    float* S = uSP;
    unsigned short* P = (unsigned short*)(uSP + 64 * SS);

    const int tid  = threadIdx.x;
    const int wave = tid >> 6;
    const int lane = tid & 63;
    const int quad = lane >> 4;
    const int l16  = lane & 15;
    const int bw   = blockIdx.x;
    const int win  = bw & (NWIN - 1);

    // ---- phase 0: stage x window fp32 -> bf16 LDS, zero pad rows 49..63 ----
    {
        const float4* xw = (const float4*)(x + (size_t)bw * (NTOK * DIM));
        for (int idx = tid; idx < NTOK * DIM / 4; idx += 512) {
            int row = idx / 48, c4 = idx - row * 48;
            float4 v = xw[idx];
            unsigned int lo = (unsigned int)f2bf(v.x) | ((unsigned int)f2bf(v.y) << 16);
            unsigned int hi = (unsigned int)f2bf(v.z) | ((unsigned int)f2bf(v.w) << 16);
            *(uint2*)&sx[row * XS + c4 * 4] = make_uint2(lo, hi);
        }
        for (int idx = tid; idx < 15 * 24; idx += 512) {
            int row = 49 + idx / 24, c8 = idx - (idx / 24) * 24;
            *(uint4*)&sx[row * XS + c8 * 8] = make_uint4(0, 0, 0, 0);
        }
    }
    __syncthreads();

    // ---- phase 1: QKV = X * Wqkv^T + b  (MFMA; B-frags from L2-resident bf16 weights) ----
    // NOTE: r-loops MUST be compile-time unrolled with static acc indices;
    // a runtime trip count (round-2 bug) demoted acc[][] to scratch -> 8 GB
    // of hidden HBM traffic.
    {
        f32x4 acc[5][4];
        #pragma unroll
        for (int r = 0; r < 5; ++r)
            #pragma unroll
            for (int mt = 0; mt < 4; ++mt) acc[r][mt] = (f32x4){0.f, 0.f, 0.f, 0.f};
        for (int k0 = 0; k0 < DIM; k0 += 32) {
            short8 af[4];
            #pragma unroll
            for (int mt = 0; mt < 4; ++mt)
                af[mt] = *(const short8*)&sx[(mt * 16 + l16) * XS + k0 + quad * 8];
            #pragma unroll
            for (int r = 0; r < 5; ++r) {
                if (wave >= 4 && r == 4) continue;   // 36 N-tiles over 8 waves
                int n0 = (wave + 8 * r) * 16;
                short8 bf = *(const short8*)(wqkv + (n0 + l16) * DIM + k0 + quad * 8);
                #pragma unroll
                for (int mt = 0; mt < 4; ++mt)
                    acc[r][mt] = __builtin_amdgcn_mfma_f32_16x16x32_bf16(af[mt], bf, acc[r][mt], 0, 0, 0);
            }
        }
        __syncthreads();   // all sx reads done before K overwrites the union region
        #pragma unroll
        for (int r = 0; r < 5; ++r) {
            if (wave >= 4 && r == 4) continue;
            int col = (wave + 8 * r) * 16 + l16;
            float cb = qkv_b[col];
            #pragma unroll
            for (int mt = 0; mt < 4; ++mt) {
                if (r >= 3) {
                    // t = wave+8r >= 24 -> always V; 4 rr values are contiguous
                    // along sv's fast (token) dim -> single uint2 write.
                    unsigned int lo = (unsigned int)f2bf(acc[r][mt][0] + cb) |
                                      ((unsigned int)f2bf(acc[r][mt][1] + cb) << 16);
                    unsigned int hi = (unsigned int)f2bf(acc[r][mt][2] + cb) |
                                      ((unsigned int)f2bf(acc[r][mt][3] + cb) << 16);
                    *(uint2*)&sv[(col - 384) * VS + mt * 16 + quad * 4] = make_uint2(lo, hi);
                } else {
                    #pragma unroll
                    for (int rr = 0; rr < 4; ++rr) {
                        int m = mt * 16 + quad * 4 + rr;    // C/D: row=quad*4+reg, col=l16
                        unsigned short bv = f2bf(acc[r][mt][rr] + cb);
                        if (col < 192) sq[m * XS + col] = bv;
                        else           kstage[m * XS + (col - 192)] = bv;
                    }
                }
            }
        }
    }
    __syncthreads();

    // ---- K -> registers: each wave snapshots its 12 B-fragments ----
    short8 kf[2][HEADS];
    #pragma unroll
    for (int tt = 0; tt < 2; ++tt) {
        int t = wave * 2 + tt, nt = t & 3;
        #pragma unroll
        for (int h = 0; h < HEADS; ++h)
            kf[tt][h] = *(const short8*)&kstage[(nt * 16 + l16) * XS + h * 32 + quad * 8];
    }
    __syncthreads();   // K reads done before 2a writes S into the same region

    const float scale = 0.17677669529663687f;
    const float* maskw = maskp + win * (NTOK * NTOK);

    #pragma unroll
    for (int h = 0; h < HEADS; ++h) {
        // ---- 2a: S = scale * Q_h K_h^T + (bias+mask) (16 tiles, 2 per wave) ----
        {
            f32x4 zz = {0.f, 0.f, 0.f, 0.f};
            const float* cw = CMB ? (cmbp + ((size_t)win * HEADS + h) * (NTOK * NTOK))
                                  : (biasp + h * (NTOK * NTOK));
            #pragma unroll
            for (int tt = 0; tt < 2; ++tt) {
                int t = wave * 2 + tt;
                int mt = t >> 2, nt = t & 3;
                short8 af = *(const short8*)&sq[(mt * 16 + l16) * XS + h * 32 + quad * 8];
                f32x4 d = __builtin_amdgcn_mfma_f32_16x16x32_bf16(af, kf[tt][h], zz, 0, 0, 0);
                #pragma unroll
                for (int rr = 0; rr < 4; ++rr) {
                    int i = mt * 16 + quad * 4 + rr;
                    int j = nt * 16 + l16;
                    if (i < NTOK && j < NTOK) {   // pads never read by 2b
                        float add = CMB ? cw[i * NTOK + j]
                                        : (cw[i * NTOK + j] + maskw[i * NTOK + j]);
                        S[i * SS + j] = d[rr] * scale + add;
                    }
                }
            }
        }
        __syncthreads();
        // ---- 2b: softmax rows (8 threads/row) -> bf16 P (unnormalized), sinv ----
        if (tid < 392) {
            int i = tid >> 3, s = tid & 7;
            float m = -1e30f;
            for (int jj = 0; jj < 7; ++jj) {
                int j = s + 8 * jj;
                if (j < NTOK) m = fmaxf(m, S[i * SS + j]);
            }
            for (int o = 1; o < 8; o <<= 1) m = fmaxf(m, __shfl_xor(m, o));
            float sum = 0.f;
            #pragma unroll
            for (int jj = 0; jj < 8; ++jj) {
                int j = s + 8 * jj;                    // covers 0..63 (pads -> 0)
                float e = 0.f;
                if (j < NTOK) { e = __expf(S[i * SS + j] - m); sum += e; }
                P[i * PS + j] = f2bf(e);
            }
            for (int o = 1; o < 8; o <<= 1) sum += __shfl_xor(sum, o);
            if (s == 0) sinv[i] = 1.f / sum;
        }
        __syncthreads();
        // ---- 2c: O_h = (P V) * sinv -> bf16 into sq cols [32h, 32h+32)  ----
        // sq cols of head h are dead after the 2b barrier (all waves passed 2a).
        // Pad rows 49..63 get explicit zeros so the proj A-operand is clean.
        {
            int mt = wave >> 1, nt = wave & 1;
            f32x4 acc = {0.f, 0.f, 0.f, 0.f};
            #pragma unroll
            for (int k0 = 0; k0 < 64; k0 += 32) {
                short8 af = *(const short8*)&P[(mt * 16 + l16) * PS + k0 + quad * 8];
                short8 bf = *(const short8*)&sv[(h * 32 + nt * 16 + l16) * VS + k0 + quad * 8];
                acc = __builtin_amdgcn_mfma_f32_16x16x32_bf16(af, bf, acc, 0, 0, 0);
            }
            #pragma unroll
            for (int rr = 0; rr < 4; ++rr) {
                int i = mt * 16 + quad * 4 + rr;
                unsigned short ov = 0;
                if (i < NTOK) ov = f2bf(acc[rr] * sinv[i]);
                sq[i * XS + h * 32 + nt * 16 + l16] = ov;
            }
        }
        // no end-of-loop barrier needed: next 2a writes S only (disjoint from P/sv/sinv)
        // and reads sq cols of head h+1 (disjoint from this 2c's writes to cols of h);
        // the post-2a barrier orders this 2c's P/sinv reads before next 2b's writes.
    }
    __syncthreads();

    // ---- phase 3: fused output projection  out = O @ proj_w^T + proj_b ----
    // A = sq (64x192 bf16, pad rows zeroed), B = wproj (L2-resident).
    // 48 output tiles: waves split 2-way on M (mh) x 4-way on N (wv), 3 N-tiles each.
    {
        const int mh = wave >> 2;    // 0..1 -> mt pair {2mh, 2mh+1}
        const int wv = wave & 3;     // 0..3 -> n-tiles wv, wv+4, wv+8
        f32x4 pacc[3][2];
        #pragma unroll
        for (int r = 0; r < 3; ++r)
            #pragma unroll
            for (int mi = 0; mi < 2; ++mi) pacc[r][mi] = (f32x4){0.f, 0.f, 0.f, 0.f};
        for (int k0 = 0; k0 < DIM; k0 += 32) {
            short8 af[2];
            #pragma unroll
            for (int mi = 0; mi < 2; ++mi)
                af[mi] = *(const short8*)&sq[((mh * 2 + mi) * 16 + l16) * XS + k0 + quad * 8];
            #pragma unroll
            for (int r = 0; r < 3; ++r) {
                int n0 = (wv + 4 * r) * 16;
                short8 bf = *(const short8*)(wproj + (n0 + l16) * DIM + k0 + quad * 8);
                #pragma unroll
                for (int mi = 0; mi < 2; ++mi)
                    pacc[r][mi] = __builtin_amdgcn_mfma_f32_16x16x32_bf16(af[mi], bf, pacc[r][mi], 0, 0, 0);
            }
        }
        #pragma unroll
        for (int r = 0; r < 3; ++r) {
            int n0 = (wv + 4 * r) * 16;
            float cb = proj_b[n0 + l16];
            #pragma unroll
            for (int mi = 0; mi < 2; ++mi) {
                #pragma unroll
                for (int rr = 0; rr < 4; ++rr) {
                    int m = (mh * 2 + mi) * 16 + quad * 4 + rr;
                    if (m < NTOK)
                        out[((size_t)bw * NTOK + m) * DIM + n0 + l16] = pacc[r][mi][rr] + cb;
                }
            }
        }
    }
}

extern "C" void kernel_launch(void* const* d_in, const int* in_sizes, int n_in,
                              void* d_out, int out_size, void* d_ws, size_t ws_size,
                              hipStream_t stream) {
    const float* x      = (const float*)d_in[0];
    const int*   rpi    = (const int*)d_in[1];
    const float* maskp  = (const float*)d_in[2];
    const float* qkv_w  = (const float*)d_in[3];
    const float* qkv_b  = (const float*)d_in[4];
    const float* proj_w = (const float*)d_in[5];
    const float* proj_b = (const float*)d_in[6];
    const float* rpb    = (const float*)d_in[7];
    float* out = (float*)d_out;

    float* bias = (float*)d_ws;                                   // 57624 B
    unsigned short* wqkv  = (unsigned short*)d_ws + WQKV_SOFF;    // 221184 B
    unsigned short* wproj = (unsigned short*)d_ws + WPROJ_SOFF;   // 73728 B
    float* cmb = nullptr;                                         // 3.69 MB (optional)
    if (ws_size >= CMB_BOFF + (size_t)CMB_ELEMS * 4)
        cmb = (float*)((char*)d_ws + CMB_BOFF);

    wa_prep_kernel<<<640, 256, 0, stream>>>(rpi, rpb, qkv_w, proj_w, maskp,
                                            bias, wqkv, wproj, cmb);
    if (cmb)
        wa_attn_kernel<true><<<4096, 512, 0, stream>>>(x, maskp, wqkv, qkv_b, bias,
                                                       wproj, proj_b, cmb, out);
    else
        wa_attn_kernel<false><<<4096, 512, 0, stream>>>(x, maskp, wqkv, qkv_b, bias,
                                                        wproj, proj_b, cmb, out);
}

// Round 5
// 690.834 us; speedup vs baseline: 1.0160x; 1.0160x over previous
//
#include <hip/hip_runtime.h>

#define DIM    192
#define HEADS  6
#define NTOK   49
#define NWIN   64

typedef __attribute__((ext_vector_type(8))) short short8;
typedef __attribute__((ext_vector_type(4))) float f32x4;

// LDS strides (elements). All bf16 row strides give 16B-aligned ds_read_b128
// (stride*2 % 16 == 0) and bank stride 4 (2-way conflict = free per m136).
#define XS 200   // sx / sq / kstage row stride (bf16), 192 cols + pad
#define VS 72    // sv (V^T) row stride (bf16), 64 tokens + pad
#define SS 65    // S row stride (fp32)
#define PS 72    // P row stride (bf16)

#define BIAS_ELEMS (HEADS * NTOK * NTOK)             // 14406 floats
#define WQKV_SOFF   28864                            // ushort offset in ws (57728 B)
#define WQKV_ELEMS  (3 * DIM * DIM)                  // 110592
#define WPROJ_SOFF  (WQKV_SOFF + WQKV_ELEMS)         // 139456
#define WPROJ_ELEMS (DIM * DIM)                      // 36864
#define CMB_BOFF    ((size_t)(WPROJ_SOFF + WPROJ_ELEMS) * 2)   // byte offset of cmb in ws
#define CMB_ELEMS   (NWIN * HEADS * NTOK * NTOK)     // 921984 floats (3.69 MB)

__device__ __forceinline__ unsigned short f2bf(float f) {
    unsigned int u = __float_as_uint(f);
    u += 0x7FFFu + ((u >> 16) & 1u);   // round-to-nearest-even
    return (unsigned short)(u >> 16);
}

// ---------------- K1: bias gather + bf16 weight conversion (+ cmb table) ----------------
__global__ void wa_prep_kernel(const int* __restrict__ rpi,
                               const float* __restrict__ rpb,
                               const float* __restrict__ qkv_w,
                               const float* __restrict__ proj_w,
                               const float* __restrict__ maskp,
                               float* __restrict__ bias,
                               unsigned short* __restrict__ wqkv,
                               unsigned short* __restrict__ wproj,
                               float* __restrict__ cmb) {
    __shared__ int is64_s;
    if (threadIdx.x < 64) {
        int z = (rpi[2 * (int)threadIdx.x + 1] == 0) ? 1 : 0;
        unsigned long long b = __ballot(z);
        if (threadIdx.x == 0) is64_s = (__popcll(b) >= 48) ? 1 : 0;
    }
    __syncthreads();
    const int is64 = is64_s;
    const int base3 = BIAS_ELEMS + WQKV_ELEMS + WPROJ_ELEMS;
    const int total = base3 + (cmb ? CMB_ELEMS : 0);
    for (int idx = blockIdx.x * blockDim.x + threadIdx.x; idx < total;
         idx += gridDim.x * blockDim.x) {
        if (idx < BIAS_ELEMS) {
            int h  = idx / (NTOK * NTOK);
            int nm = idx - h * (NTOK * NTOK);
            int r  = is64 ? rpi[2 * nm] : rpi[nm];
            bias[idx] = rpb[r * HEADS + h];
        } else if (idx < BIAS_ELEMS + WQKV_ELEMS) {
            int i = idx - BIAS_ELEMS;
            wqkv[i] = f2bf(qkv_w[i]);
        } else if (idx < base3) {
            int i = idx - BIAS_ELEMS - WQKV_ELEMS;
            wproj[i] = f2bf(proj_w[i]);
        } else {
            // cmb[win][h][i*49+j] = rpb[rpi[i*49+j]][h] + mask[win][i*49+j]
            int i2  = idx - base3;
            int win = i2 / (HEADS * NTOK * NTOK);
            int rem = i2 - win * (HEADS * NTOK * NTOK);
            int h   = rem / (NTOK * NTOK);
            int nm  = rem - h * (NTOK * NTOK);
            int r   = is64 ? rpi[2 * nm] : rpi[nm];
            cmb[i2] = rpb[r * HEADS + h] + maskp[win * (NTOK * NTOK) + nm];
        }
    }
}

// ---------------- K2: fused QKV + attention + output projection ----------------
// One block per window, target 2 blocks/CU (LDS 79360 B <= 80 KiB).
//
// REGISTER MODEL (R1/R2/R4 counter evidence): rocprof VGPR_Count EXCLUDES
// AGPRs (MFMA accumulators; gfx950 unified file). Occupancy = floor(512-reg
// pool / (VGPR+AGPR)) waves/EU. R4: 72V + 80A(acc[5][4]) = 152 -> 3 waves/EU
// -> 1 block/CU (24% occ, dur 527). R2: (512,4) capped total at 128 (=512/4:
// 2nd arg IS min waves/EU per guide) -> 2 blocks (45%) but spilled 168->128
// (+156 MB scratch traffic). Fix: BALANCED phase-1 tiling, acc[9][2] = 72
// AGPR (was 80 imbalanced), af[2] (was 4) -> natural total ~112 <= 128 ->
// (512,4) pins 4 waves/EU with NO spills.
//
// K lives in REGISTERS during the head loop (48 VGPR, phase-1 acc dead by
// then). The union region uSP serves three lives: sx (staged x) -> kstage (K)
// -> S (fp32) + P (bf16). After head h, sq cols [32h,32h+32) hold the
// attention output (Q dead), and phase 3 runs the output projection in-block
// against L2-resident wproj.
template <bool CMB>
__global__ __launch_bounds__(512, 4)
void wa_attn_kernel(const float* __restrict__ x,
                    const float* __restrict__ maskp,
                    const unsigned short* __restrict__ wqkv,
                    const float* __restrict__ qkv_b,
                    const float* __restrict__ biasp,
                    const unsigned short* __restrict__ wproj,
                    const float* __restrict__ proj_b,
                    const float* __restrict__ cmbp,
                    float* __restrict__ out) {
    __shared__ __attribute__((aligned(16))) float uSP[64 * SS + 64 * (PS / 2)]; // 25856 B
    __shared__ __attribute__((aligned(16))) unsigned short sq[64 * XS];   // 25600 B
    __shared__ __attribute__((aligned(16))) unsigned short sv[DIM * VS];  // 27648 B (V^T)
    __shared__ float sinv[64];

    unsigned short* sx     = (unsigned short*)uSP;
    unsigned short* kstage = (unsigned short*)uSP;
    float* S = uSP;
    unsigned short* P = (unsigned short*)(uSP + 64 * SS);

    const int tid  = threadIdx.x;
    const int wave = tid >> 6;
    const int lane = tid & 63;
    const int quad = lane >> 4;
    const int l16  = lane & 15;
    const int bw   = blockIdx.x;
    const int win  = bw & (NWIN - 1);

    // ---- phase 0: stage x window fp32 -> bf16 LDS, zero pad rows 49..63 ----
    {
        const float4* xw = (const float4*)(x + (size_t)bw * (NTOK * DIM));
        for (int idx = tid; idx < NTOK * DIM / 4; idx += 512) {
            int row = idx / 48, c4 = idx - row * 48;
            float4 v = xw[idx];
            unsigned int lo = (unsigned int)f2bf(v.x) | ((unsigned int)f2bf(v.y) << 16);
            unsigned int hi = (unsigned int)f2bf(v.z) | ((unsigned int)f2bf(v.w) << 16);
            *(uint2*)&sx[row * XS + c4 * 4] = make_uint2(lo, hi);
        }
        for (int idx = tid; idx < 15 * 24; idx += 512) {
            int row = 49 + idx / 24, c8 = idx - (idx / 24) * 24;
            *(uint4*)&sx[row * XS + c8 * 8] = make_uint4(0, 0, 0, 0);
        }
    }
    __syncthreads();

    // ---- phase 1: QKV = X * Wqkv^T + b  (MFMA; B-frags from L2-resident bf16 weights) ----
    // Balanced: wave (wm,wn) owns M-tiles {2wm,2wm+1} x N-tiles {wn+4r, r=0..8}
    // = 18 tiles/wave exactly (144 = 4x36 total). acc[9][2] = 72 AGPR.
    // NOTE: loops MUST be compile-time unrolled with static acc indices;
    // a runtime trip count once demoted acc[][] to scratch -> 8 GB hidden HBM.
    {
        const int wm = wave >> 2;    // 0..1
        const int wn = wave & 3;     // 0..3
        f32x4 acc[9][2];
        #pragma unroll
        for (int r = 0; r < 9; ++r)
            #pragma unroll
            for (int mi = 0; mi < 2; ++mi) acc[r][mi] = (f32x4){0.f, 0.f, 0.f, 0.f};
        for (int k0 = 0; k0 < DIM; k0 += 32) {
            short8 af[2];
            #pragma unroll
            for (int mi = 0; mi < 2; ++mi)
                af[mi] = *(const short8*)&sx[((wm * 2 + mi) * 16 + l16) * XS + k0 + quad * 8];
            #pragma unroll
            for (int r = 0; r < 9; ++r) {
                int n0 = (wn + 4 * r) * 16;
                short8 bf = *(const short8*)(wqkv + (n0 + l16) * DIM + k0 + quad * 8);
                #pragma unroll
                for (int mi = 0; mi < 2; ++mi)
                    acc[r][mi] = __builtin_amdgcn_mfma_f32_16x16x32_bf16(af[mi], bf, acc[r][mi], 0, 0, 0);
            }
        }
        __syncthreads();   // all sx reads done before K overwrites the union region
        #pragma unroll
        for (int r = 0; r < 9; ++r) {
            int col = (wn + 4 * r) * 16 + l16;   // r<3: Q, 3<=r<6: K, r>=6: V
            float cb = qkv_b[col];
            #pragma unroll
            for (int mi = 0; mi < 2; ++mi) {
                int mbase = (wm * 2 + mi) * 16 + quad * 4;   // C/D: row=quad*4+reg
                if (r >= 6) {
                    // V: 4 rr values are consecutive tokens along sv's fast dim
                    // -> single uint2 write (V stored transposed).
                    unsigned int lo = (unsigned int)f2bf(acc[r][mi][0] + cb) |
                                      ((unsigned int)f2bf(acc[r][mi][1] + cb) << 16);
                    unsigned int hi = (unsigned int)f2bf(acc[r][mi][2] + cb) |
                                      ((unsigned int)f2bf(acc[r][mi][3] + cb) << 16);
                    *(uint2*)&sv[(col - 384) * VS + mbase] = make_uint2(lo, hi);
                } else if (r >= 3) {
                    #pragma unroll
                    for (int rr = 0; rr < 4; ++rr)
                        kstage[(mbase + rr) * XS + (col - 192)] = f2bf(acc[r][mi][rr] + cb);
                } else {
                    #pragma unroll
                    for (int rr = 0; rr < 4; ++rr)
                        sq[(mbase + rr) * XS + col] = f2bf(acc[r][mi][rr] + cb);
                }
            }
        }
    }
    __syncthreads();

    // ---- K -> registers: each wave snapshots its 12 B-fragments ----
    short8 kf[2][HEADS];
    #pragma unroll
    for (int tt = 0; tt < 2; ++tt) {
        int t = wave * 2 + tt, nt = t & 3;
        #pragma unroll
        for (int h = 0; h < HEADS; ++h)
            kf[tt][h] = *(const short8*)&kstage[(nt * 16 + l16) * XS + h * 32 + quad * 8];
    }
    __syncthreads();   // K reads done before 2a writes S into the same region

    const float scale = 0.17677669529663687f;
    const float* maskw = maskp + win * (NTOK * NTOK);

    #pragma unroll
    for (int h = 0; h < HEADS; ++h) {
        // ---- 2a: S = scale * Q_h K_h^T + (bias+mask) (16 tiles, 2 per wave) ----
        {
            f32x4 zz = {0.f, 0.f, 0.f, 0.f};
            const float* cw = CMB ? (cmbp + ((size_t)win * HEADS + h) * (NTOK * NTOK))
                                  : (biasp + h * (NTOK * NTOK));
            #pragma unroll
            for (int tt = 0; tt < 2; ++tt) {
                int t = wave * 2 + tt;
                int mt = t >> 2, nt = t & 3;
                short8 af = *(const short8*)&sq[(mt * 16 + l16) * XS + h * 32 + quad * 8];
                f32x4 d = __builtin_amdgcn_mfma_f32_16x16x32_bf16(af, kf[tt][h], zz, 0, 0, 0);
                #pragma unroll
                for (int rr = 0; rr < 4; ++rr) {
                    int i = mt * 16 + quad * 4 + rr;
                    int j = nt * 16 + l16;
                    if (i < NTOK && j < NTOK) {   // pads never read by 2b
                        float add = CMB ? cw[i * NTOK + j]
                                        : (cw[i * NTOK + j] + maskw[i * NTOK + j]);
                        S[i * SS + j] = d[rr] * scale + add;
                    }
                }
            }
        }
        __syncthreads();
        // ---- 2b: softmax rows (8 threads/row) -> bf16 P (unnormalized), sinv ----
        if (tid < 392) {
            int i = tid >> 3, s = tid & 7;
            float m = -1e30f;
            for (int jj = 0; jj < 7; ++jj) {
                int j = s + 8 * jj;
                if (j < NTOK) m = fmaxf(m, S[i * SS + j]);
            }
            for (int o = 1; o < 8; o <<= 1) m = fmaxf(m, __shfl_xor(m, o));
            float sum = 0.f;
            #pragma unroll
            for (int jj = 0; jj < 8; ++jj) {
                int j = s + 8 * jj;                    // covers 0..63 (pads -> 0)
                float e = 0.f;
                if (j < NTOK) { e = __expf(S[i * SS + j] - m); sum += e; }
                P[i * PS + j] = f2bf(e);
            }
            for (int o = 1; o < 8; o <<= 1) sum += __shfl_xor(sum, o);
            if (s == 0) sinv[i] = 1.f / sum;
        }
        __syncthreads();
        // ---- 2c: O_h = (P V) * sinv -> bf16 into sq cols [32h, 32h+32)  ----
        // sq cols of head h are dead after the 2b barrier (all waves passed 2a).
        // Pad rows 49..63 get explicit zeros so the proj A-operand is clean.
        {
            int mt = wave >> 1, nt = wave & 1;
            f32x4 acc = {0.f, 0.f, 0.f, 0.f};
            #pragma unroll
            for (int k0 = 0; k0 < 64; k0 += 32) {
                short8 af = *(const short8*)&P[(mt * 16 + l16) * PS + k0 + quad * 8];
                short8 bf = *(const short8*)&sv[(h * 32 + nt * 16 + l16) * VS + k0 + quad * 8];
                acc = __builtin_amdgcn_mfma_f32_16x16x32_bf16(af, bf, acc, 0, 0, 0);
            }
            #pragma unroll
            for (int rr = 0; rr < 4; ++rr) {
                int i = mt * 16 + quad * 4 + rr;
                unsigned short ov = 0;
                if (i < NTOK) ov = f2bf(acc[rr] * sinv[i]);
                sq[i * XS + h * 32 + nt * 16 + l16] = ov;
            }
        }
        // no end-of-loop barrier needed: next 2a writes S only (disjoint from P/sv/sinv)
        // and reads sq cols of head h+1 (disjoint from this 2c's writes to cols of h);
        // the post-2a barrier orders this 2c's P/sinv reads before next 2b's writes.
    }
    __syncthreads();

    // ---- phase 3: fused output projection  out = O @ proj_w^T + proj_b ----
    // A = sq (64x192 bf16, pad rows zeroed), B = wproj (L2-resident).
    // 48 output tiles: waves split 2-way on M (mh) x 4-way on N (wv), 3 N-tiles each.
    {
        const int mh = wave >> 2;    // 0..1 -> mt pair {2mh, 2mh+1}
        const int wv = wave & 3;     // 0..3 -> n-tiles wv, wv+4, wv+8
        f32x4 pacc[3][2];
        #pragma unroll
        for (int r = 0; r < 3; ++r)
            #pragma unroll
            for (int mi = 0; mi < 2; ++mi) pacc[r][mi] = (f32x4){0.f, 0.f, 0.f, 0.f};
        for (int k0 = 0; k0 < DIM; k0 += 32) {
            short8 af[2];
            #pragma unroll
            for (int mi = 0; mi < 2; ++mi)
                af[mi] = *(const short8*)&sq[((mh * 2 + mi) * 16 + l16) * XS + k0 + quad * 8];
            #pragma unroll
            for (int r = 0; r < 3; ++r) {
                int n0 = (wv + 4 * r) * 16;
                short8 bf = *(const short8*)(wproj + (n0 + l16) * DIM + k0 + quad * 8);
                #pragma unroll
                for (int mi = 0; mi < 2; ++mi)
                    pacc[r][mi] = __builtin_amdgcn_mfma_f32_16x16x32_bf16(af[mi], bf, pacc[r][mi], 0, 0, 0);
            }
        }
        #pragma unroll
        for (int r = 0; r < 3; ++r) {
            int n0 = (wv + 4 * r) * 16;
            float cb = proj_b[n0 + l16];
            #pragma unroll
            for (int mi = 0; mi < 2; ++mi) {
                #pragma unroll
                for (int rr = 0; rr < 4; ++rr) {
                    int m = (mh * 2 + mi) * 16 + quad * 4 + rr;
                    if (m < NTOK)
                        out[((size_t)bw * NTOK + m) * DIM + n0 + l16] = pacc[r][mi][rr] + cb;
                }
            }
        }
    }
}

extern "C" void kernel_launch(void* const* d_in, const int* in_sizes, int n_in,
                              void* d_out, int out_size, void* d_ws, size_t ws_size,
                              hipStream_t stream) {
    const float* x      = (const float*)d_in[0];
    const int*   rpi    = (const int*)d_in[1];
    const float* maskp  = (const float*)d_in[2];
    const float* qkv_w  = (const float*)d_in[3];
    const float* qkv_b  = (const float*)d_in[4];
    const float* proj_w = (const float*)d_in[5];
    const float* proj_b = (const float*)d_in[6];
    const float* rpb    = (const float*)d_in[7];
    float* out = (float*)d_out;

    float* bias = (float*)d_ws;                                   // 57624 B
    unsigned short* wqkv  = (unsigned short*)d_ws + WQKV_SOFF;    // 221184 B
    unsigned short* wproj = (unsigned short*)d_ws + WPROJ_SOFF;   // 73728 B
    float* cmb = nullptr;                                         // 3.69 MB (optional)
    if (ws_size >= CMB_BOFF + (size_t)CMB_ELEMS * 4)
        cmb = (float*)((char*)d_ws + CMB_BOFF);

    wa_prep_kernel<<<640, 256, 0, stream>>>(rpi, rpb, qkv_w, proj_w, maskp,
                                            bias, wqkv, wproj, cmb);
    if (cmb)
        wa_attn_kernel<true><<<4096, 512, 0, stream>>>(x, maskp, wqkv, qkv_b, bias,
                                                       wproj, proj_b, cmb, out);
    else
        wa_attn_kernel<false><<<4096, 512, 0, stream>>>(x, maskp, wqkv, qkv_b, bias,
                                                        wproj, proj_b, cmb, out);
}

// Round 6
// 629.750 us; speedup vs baseline: 1.1146x; 1.0970x over previous
//
#include <hip/hip_runtime.h>

#define DIM    192
#define HEADS  6
#define NTOK   49
#define NWIN   64

typedef __attribute__((ext_vector_type(8))) short short8;
typedef __attribute__((ext_vector_type(4))) float f32x4;

// LDS strides (elements). All bf16 row strides give 16B-aligned ds_read_b128
// (stride*2 % 16 == 0) and bank stride 4 (2-way conflict = free per m136).
#define XS 200   // sx / sq / kstage row stride (bf16), 192 cols + pad
#define VS 72    // sv (V^T) row stride (bf16), 64 tokens + pad
#define SS 65    // S row stride (fp32)
#define PS 72    // P row stride (bf16)

#define BIAS_ELEMS (HEADS * NTOK * NTOK)             // 14406 floats
#define WQKV_SOFF   28864                            // ushort offset in ws (57728 B)
#define WQKV_ELEMS  (3 * DIM * DIM)                  // 110592
#define WPROJ_SOFF  (WQKV_SOFF + WQKV_ELEMS)         // 139456
#define WPROJ_ELEMS (DIM * DIM)                      // 36864
#define CMB_BOFF    ((size_t)(WPROJ_SOFF + WPROJ_ELEMS) * 2)   // byte offset of cmb in ws
#define CMB_ELEMS   (NWIN * HEADS * NTOK * NTOK)     // 921984 floats (3.69 MB)

__device__ __forceinline__ unsigned short f2bf(float f) {
    unsigned int u = __float_as_uint(f);
    u += 0x7FFFu + ((u >> 16) & 1u);   // round-to-nearest-even
    return (unsigned short)(u >> 16);
}

// ---------------- K1: bias gather + bf16 weight conversion (+ cmb table) ----------------
__global__ void wa_prep_kernel(const int* __restrict__ rpi,
                               const float* __restrict__ rpb,
                               const float* __restrict__ qkv_w,
                               const float* __restrict__ proj_w,
                               const float* __restrict__ maskp,
                               float* __restrict__ bias,
                               unsigned short* __restrict__ wqkv,
                               unsigned short* __restrict__ wproj,
                               float* __restrict__ cmb) {
    __shared__ int is64_s;
    if (threadIdx.x < 64) {
        int z = (rpi[2 * (int)threadIdx.x + 1] == 0) ? 1 : 0;
        unsigned long long b = __ballot(z);
        if (threadIdx.x == 0) is64_s = (__popcll(b) >= 48) ? 1 : 0;
    }
    __syncthreads();
    const int is64 = is64_s;
    const int base3 = BIAS_ELEMS + WQKV_ELEMS + WPROJ_ELEMS;
    const int total = base3 + (cmb ? CMB_ELEMS : 0);
    for (int idx = blockIdx.x * blockDim.x + threadIdx.x; idx < total;
         idx += gridDim.x * blockDim.x) {
        if (idx < BIAS_ELEMS) {
            int h  = idx / (NTOK * NTOK);
            int nm = idx - h * (NTOK * NTOK);
            int r  = is64 ? rpi[2 * nm] : rpi[nm];
            bias[idx] = rpb[r * HEADS + h];
        } else if (idx < BIAS_ELEMS + WQKV_ELEMS) {
            int i = idx - BIAS_ELEMS;
            wqkv[i] = f2bf(qkv_w[i]);
        } else if (idx < base3) {
            int i = idx - BIAS_ELEMS - WQKV_ELEMS;
            wproj[i] = f2bf(proj_w[i]);
        } else {
            // cmb[win][h][i*49+j] = rpb[rpi[i*49+j]][h] + mask[win][i*49+j]
            int i2  = idx - base3;
            int win = i2 / (HEADS * NTOK * NTOK);
            int rem = i2 - win * (HEADS * NTOK * NTOK);
            int h   = rem / (NTOK * NTOK);
            int nm  = rem - h * (NTOK * NTOK);
            int r   = is64 ? rpi[2 * nm] : rpi[nm];
            cmb[i2] = rpb[r * HEADS + h] + maskp[win * (NTOK * NTOK) + nm];
        }
    }
}

// ---------------- K2: fused QKV + attention + output projection ----------------
// One block per window, 2 blocks/CU (LDS 79360 B <= 80 KiB).
//
// REGISTER MODEL (R1/R2/R4/R5 counter evidence): rocprof VGPR_Count EXCLUDES
// AGPRs (gfx950 unified file). Occupancy = floor(512 / (VGPR+AGPR)) waves/EU;
// __launch_bounds__ 2nd arg = min waves/EU -> total-reg cap 512/N.
//   R4: natural 72V+80A = 152 -> 3 waves/EU -> 1 block/CU (24% occ).
//   R2/R5: (512,4) cap 128 with natural demand >128 -> VGPR_Count pinned at
//   64 and 150-250 MB of scratch spill traffic (FETCH/WRITE inflation).
// Conclusion: phase 1 must NATURALLY fit 128. Fix: CHUNKED QKV GEMM —
// process Q, V, K thirds sequentially, acc[3][2]=24 AGPR each (fresh per
// chunk), 3 B-streams in flight. Peak ~90 regs -> (512,4) holds with no
// spill. K chunk LAST: its epilogue overwrites sx (kstage alias); a uniform
// barrier before that epilogue protects all waves' sx reads.
//
// K lives in REGISTERS during the head loop (48 VGPR, phase-1 acc dead).
// uSP union: sx (staged x) -> kstage (K) -> S (fp32) + P (bf16). After head
// h, sq cols [32h,32h+32) hold the attention output (Q dead); phase 3 runs
// the output projection in-block against L2-resident wproj.
template <bool CMB>
__global__ __launch_bounds__(512, 4)
void wa_attn_kernel(const float* __restrict__ x,
                    const float* __restrict__ maskp,
                    const unsigned short* __restrict__ wqkv,
                    const float* __restrict__ qkv_b,
                    const float* __restrict__ biasp,
                    const unsigned short* __restrict__ wproj,
                    const float* __restrict__ proj_b,
                    const float* __restrict__ cmbp,
                    float* __restrict__ out) {
    __shared__ __attribute__((aligned(16))) float uSP[64 * SS + 64 * (PS / 2)]; // 25856 B
    __shared__ __attribute__((aligned(16))) unsigned short sq[64 * XS];   // 25600 B
    __shared__ __attribute__((aligned(16))) unsigned short sv[DIM * VS];  // 27648 B (V^T)
    __shared__ float sinv[64];

    unsigned short* sx     = (unsigned short*)uSP;
    unsigned short* kstage = (unsigned short*)uSP;
    float* S = uSP;
    unsigned short* P = (unsigned short*)(uSP + 64 * SS);

    const int tid  = threadIdx.x;
    const int wave = tid >> 6;
    const int lane = tid & 63;
    const int quad = lane >> 4;
    const int l16  = lane & 15;
    const int bw   = blockIdx.x;
    const int win  = bw & (NWIN - 1);

    // ---- phase 0: stage x window fp32 -> bf16 LDS, zero pad rows 49..63 ----
    {
        const float4* xw = (const float4*)(x + (size_t)bw * (NTOK * DIM));
        for (int idx = tid; idx < NTOK * DIM / 4; idx += 512) {
            int row = idx / 48, c4 = idx - row * 48;
            float4 v = xw[idx];
            unsigned int lo = (unsigned int)f2bf(v.x) | ((unsigned int)f2bf(v.y) << 16);
            unsigned int hi = (unsigned int)f2bf(v.z) | ((unsigned int)f2bf(v.w) << 16);
            *(uint2*)&sx[row * XS + c4 * 4] = make_uint2(lo, hi);
        }
        for (int idx = tid; idx < 15 * 24; idx += 512) {
            int row = 49 + idx / 24, c8 = idx - (idx / 24) * 24;
            *(uint4*)&sx[row * XS + c8 * 8] = make_uint4(0, 0, 0, 0);
        }
    }
    __syncthreads();

    // ---- phase 1: QKV = X * Wqkv^T + b, CHUNKED (Q, V, then K) ----
    // Per chunk: wave (wm,wn) owns M-tiles {2wm,2wm+1} x N-tiles {wn,wn+4,wn+8}
    // of the chunk's 192 cols; acc[3][2] = 24 AGPR. 6 MFMA-tiles x 6 k-steps.
    {
        const int wm = wave >> 2;    // 0..1
        const int wn = wave & 3;     // 0..3
        #pragma unroll
        for (int cc = 0; cc < 3; ++cc) {
            const int c = (cc == 0) ? 0 : (cc == 1 ? 2 : 1);   // Q, V, K(last)
            f32x4 acc[3][2];
            #pragma unroll
            for (int r = 0; r < 3; ++r)
                #pragma unroll
                for (int mi = 0; mi < 2; ++mi) acc[r][mi] = (f32x4){0.f, 0.f, 0.f, 0.f};
            for (int k0 = 0; k0 < DIM; k0 += 32) {
                short8 af[2];
                #pragma unroll
                for (int mi = 0; mi < 2; ++mi)
                    af[mi] = *(const short8*)&sx[((wm * 2 + mi) * 16 + l16) * XS + k0 + quad * 8];
                #pragma unroll
                for (int r = 0; r < 3; ++r) {
                    int n0 = c * 192 + (wn + 4 * r) * 16;
                    short8 bf = *(const short8*)(wqkv + (n0 + l16) * DIM + k0 + quad * 8);
                    #pragma unroll
                    for (int mi = 0; mi < 2; ++mi)
                        acc[r][mi] = __builtin_amdgcn_mfma_f32_16x16x32_bf16(af[mi], bf, acc[r][mi], 0, 0, 0);
                }
            }
            if (c == 1) __syncthreads();   // all sx reads done before K overwrites it
            #pragma unroll
            for (int r = 0; r < 3; ++r) {
                int ccol = (wn + 4 * r) * 16 + l16;      // col within chunk, 0..191
                float cb = qkv_b[c * 192 + ccol];
                #pragma unroll
                for (int mi = 0; mi < 2; ++mi) {
                    int mbase = (wm * 2 + mi) * 16 + quad * 4;   // C/D: row=quad*4+reg
                    if (c == 2) {
                        // V: 4 rr values are consecutive tokens along sv's fast
                        // dim -> single uint2 write (V stored transposed).
                        unsigned int lo = (unsigned int)f2bf(acc[r][mi][0] + cb) |
                                          ((unsigned int)f2bf(acc[r][mi][1] + cb) << 16);
                        unsigned int hi = (unsigned int)f2bf(acc[r][mi][2] + cb) |
                                          ((unsigned int)f2bf(acc[r][mi][3] + cb) << 16);
                        *(uint2*)&sv[ccol * VS + mbase] = make_uint2(lo, hi);
                    } else if (c == 1) {
                        #pragma unroll
                        for (int rr = 0; rr < 4; ++rr)
                            kstage[(mbase + rr) * XS + ccol] = f2bf(acc[r][mi][rr] + cb);
                    } else {
                        #pragma unroll
                        for (int rr = 0; rr < 4; ++rr)
                            sq[(mbase + rr) * XS + ccol] = f2bf(acc[r][mi][rr] + cb);
                    }
                }
            }
        }
    }
    __syncthreads();

    // ---- K -> registers: each wave snapshots its 12 B-fragments ----
    short8 kf[2][HEADS];
    #pragma unroll
    for (int tt = 0; tt < 2; ++tt) {
        int t = wave * 2 + tt, nt = t & 3;
        #pragma unroll
        for (int h = 0; h < HEADS; ++h)
            kf[tt][h] = *(const short8*)&kstage[(nt * 16 + l16) * XS + h * 32 + quad * 8];
    }
    __syncthreads();   // K reads done before 2a writes S into the same region

    const float scale = 0.17677669529663687f;
    const float* maskw = maskp + win * (NTOK * NTOK);

    #pragma unroll
    for (int h = 0; h < HEADS; ++h) {
        // ---- 2a: S = scale * Q_h K_h^T + (bias+mask) (16 tiles, 2 per wave) ----
        {
            f32x4 zz = {0.f, 0.f, 0.f, 0.f};
            const float* cw = CMB ? (cmbp + ((size_t)win * HEADS + h) * (NTOK * NTOK))
                                  : (biasp + h * (NTOK * NTOK));
            #pragma unroll
            for (int tt = 0; tt < 2; ++tt) {
                int t = wave * 2 + tt;
                int mt = t >> 2, nt = t & 3;
                short8 af = *(const short8*)&sq[(mt * 16 + l16) * XS + h * 32 + quad * 8];
                f32x4 d = __builtin_amdgcn_mfma_f32_16x16x32_bf16(af, kf[tt][h], zz, 0, 0, 0);
                #pragma unroll
                for (int rr = 0; rr < 4; ++rr) {
                    int i = mt * 16 + quad * 4 + rr;
                    int j = nt * 16 + l16;
                    if (i < NTOK && j < NTOK) {   // pads never read by 2b
                        float add = CMB ? cw[i * NTOK + j]
                                        : (cw[i * NTOK + j] + maskw[i * NTOK + j]);
                        S[i * SS + j] = d[rr] * scale + add;
                    }
                }
            }
        }
        __syncthreads();
        // ---- 2b: softmax rows (8 threads/row) -> bf16 P (unnormalized), sinv ----
        if (tid < 392) {
            int i = tid >> 3, s = tid & 7;
            float m = -1e30f;
            for (int jj = 0; jj < 7; ++jj) {
                int j = s + 8 * jj;
                if (j < NTOK) m = fmaxf(m, S[i * SS + j]);
            }
            for (int o = 1; o < 8; o <<= 1) m = fmaxf(m, __shfl_xor(m, o));
            float sum = 0.f;
            #pragma unroll
            for (int jj = 0; jj < 8; ++jj) {
                int j = s + 8 * jj;                    // covers 0..63 (pads -> 0)
                float e = 0.f;
                if (j < NTOK) { e = __expf(S[i * SS + j] - m); sum += e; }
                P[i * PS + j] = f2bf(e);
            }
            for (int o = 1; o < 8; o <<= 1) sum += __shfl_xor(sum, o);
            if (s == 0) sinv[i] = 1.f / sum;
        }
        __syncthreads();
        // ---- 2c: O_h = (P V) * sinv -> bf16 into sq cols [32h, 32h+32)  ----
        // sq cols of head h are dead after the 2b barrier (all waves passed 2a).
        // Pad rows 49..63 get explicit zeros so the proj A-operand is clean.
        {
            int mt = wave >> 1, nt = wave & 1;
            f32x4 acc = {0.f, 0.f, 0.f, 0.f};
            #pragma unroll
            for (int k0 = 0; k0 < 64; k0 += 32) {
                short8 af = *(const short8*)&P[(mt * 16 + l16) * PS + k0 + quad * 8];
                short8 bf = *(const short8*)&sv[(h * 32 + nt * 16 + l16) * VS + k0 + quad * 8];
                acc = __builtin_amdgcn_mfma_f32_16x16x32_bf16(af, bf, acc, 0, 0, 0);
            }
            #pragma unroll
            for (int rr = 0; rr < 4; ++rr) {
                int i = mt * 16 + quad * 4 + rr;
                unsigned short ov = 0;
                if (i < NTOK) ov = f2bf(acc[rr] * sinv[i]);
                sq[i * XS + h * 32 + nt * 16 + l16] = ov;
            }
        }
        // no end-of-loop barrier needed: next 2a writes S only (disjoint from P/sv/sinv)
        // and reads sq cols of head h+1 (disjoint from this 2c's writes to cols of h);
        // the post-2a barrier orders this 2c's P/sinv reads before next 2b's writes.
    }
    __syncthreads();

    // ---- phase 3: fused output projection  out = O @ proj_w^T + proj_b ----
    // A = sq (64x192 bf16, pad rows zeroed), B = wproj (L2-resident).
    // 48 output tiles: waves split 2-way on M (mh) x 4-way on N (wv), 3 N-tiles each.
    {
        const int mh = wave >> 2;    // 0..1 -> mt pair {2mh, 2mh+1}
        const int wv = wave & 3;     // 0..3 -> n-tiles wv, wv+4, wv+8
        f32x4 pacc[3][2];
        #pragma unroll
        for (int r = 0; r < 3; ++r)
            #pragma unroll
            for (int mi = 0; mi < 2; ++mi) pacc[r][mi] = (f32x4){0.f, 0.f, 0.f, 0.f};
        for (int k0 = 0; k0 < DIM; k0 += 32) {
            short8 af[2];
            #pragma unroll
            for (int mi = 0; mi < 2; ++mi)
                af[mi] = *(const short8*)&sq[((mh * 2 + mi) * 16 + l16) * XS + k0 + quad * 8];
            #pragma unroll
            for (int r = 0; r < 3; ++r) {
                int n0 = (wv + 4 * r) * 16;
                short8 bf = *(const short8*)(wproj + (n0 + l16) * DIM + k0 + quad * 8);
                #pragma unroll
                for (int mi = 0; mi < 2; ++mi)
                    pacc[r][mi] = __builtin_amdgcn_mfma_f32_16x16x32_bf16(af[mi], bf, pacc[r][mi], 0, 0, 0);
            }
        }
        #pragma unroll
        for (int r = 0; r < 3; ++r) {
            int n0 = (wv + 4 * r) * 16;
            float cb = proj_b[n0 + l16];
            #pragma unroll
            for (int mi = 0; mi < 2; ++mi) {
                #pragma unroll
                for (int rr = 0; rr < 4; ++rr) {
                    int m = (mh * 2 + mi) * 16 + quad * 4 + rr;
                    if (m < NTOK)
                        out[((size_t)bw * NTOK + m) * DIM + n0 + l16] = pacc[r][mi][rr] + cb;
                }
            }
        }
    }
}

extern "C" void kernel_launch(void* const* d_in, const int* in_sizes, int n_in,
                              void* d_out, int out_size, void* d_ws, size_t ws_size,
                              hipStream_t stream) {
    const float* x      = (const float*)d_in[0];
    const int*   rpi    = (const int*)d_in[1];
    const float* maskp  = (const float*)d_in[2];
    const float* qkv_w  = (const float*)d_in[3];
    const float* qkv_b  = (const float*)d_in[4];
    const float* proj_w = (const float*)d_in[5];
    const float* proj_b = (const float*)d_in[6];
    const float* rpb    = (const float*)d_in[7];
    float* out = (float*)d_out;

    float* bias = (float*)d_ws;                                   // 57624 B
    unsigned short* wqkv  = (unsigned short*)d_ws + WQKV_SOFF;    // 221184 B
    unsigned short* wproj = (unsigned short*)d_ws + WPROJ_SOFF;   // 73728 B
    float* cmb = nullptr;                                         // 3.69 MB (optional)
    if (ws_size >= CMB_BOFF + (size_t)CMB_ELEMS * 4)
        cmb = (float*)((char*)d_ws + CMB_BOFF);

    wa_prep_kernel<<<640, 256, 0, stream>>>(rpi, rpb, qkv_w, proj_w, maskp,
                                            bias, wqkv, wproj, cmb);
    if (cmb)
        wa_attn_kernel<true><<<4096, 512, 0, stream>>>(x, maskp, wqkv, qkv_b, bias,
                                                       wproj, proj_b, cmb, out);
    else
        wa_attn_kernel<false><<<4096, 512, 0, stream>>>(x, maskp, wqkv, qkv_b, bias,
                                                        wproj, proj_b, cmb, out);
}

// Round 7
// 609.659 us; speedup vs baseline: 1.1513x; 1.0330x over previous
//
#include <hip/hip_runtime.h>

#define DIM    192
#define HEADS  6
#define NTOK   49
#define NWIN   64

typedef __attribute__((ext_vector_type(8))) short short8;
typedef __attribute__((ext_vector_type(4))) float f32x4;

// LDS strides (elements). bf16 row strides give 16B-aligned ds_read_b128
// (stride*2 % 16 == 0) and dword bank stride 4*l16 % 32 -> 2-way (free, m136).
#define XS 200   // sx / sq / kstage row stride (bf16)
#define VS 72    // sv (V^T) row stride
#define PS 72    // P row stride

// LDS carve (single array, manual offsets — layout order matters: P's pad-row
// reads [26656,28816) intentionally land in sq (finite bf16, rows discarded)):
//   [0,26656)      uSPr: phase0/1 sx (25600) -> head loop K rows [0,49) (19600)
//                  + P[64][PS] at elem 9800 (P pads >= row 49 alias sq)
//   [26656,52256)  sq: Q (scaled, bf16) -> per-head O columns
//   [52256,79904)  sv: V^T
#define USP_BYTES   26656
#define P_EOFF      9800      // 49*200: P starts after 49 real K rows
#define LDS_USHORTS ((USP_BYTES + 64 * XS * 2 + DIM * VS * 2) / 2)   // 39952

#define BIAS_ELEMS (HEADS * NTOK * NTOK)             // 14406 floats
#define WQKV_SOFF   28864                            // ushort offset in ws
#define WQKV_ELEMS  (3 * DIM * DIM)                  // 110592
#define WPROJ_SOFF  (WQKV_SOFF + WQKV_ELEMS)
#define WPROJ_ELEMS (DIM * DIM)                      // 36864
#define CMB_BOFF    ((size_t)(WPROJ_SOFF + WPROJ_ELEMS) * 2)   // 352640 B
#define CMB2_ELEMS  (NWIN * HEADS * NTOK * 64)       // 1204224 floats (4.82 MB)

__device__ __forceinline__ unsigned short f2bf(float f) {
    unsigned int u = __float_as_uint(f);
    u += 0x7FFFu + ((u >> 16) & 1u);   // round-to-nearest-even
    return (unsigned short)(u >> 16);
}

// ---------------- K1: bias gather + bf16 weights + padded cmb2 table ----------------
// cmb2[win][h][q][64]: bias+mask with k padded 49->64 (zeros) so K2 can load
// float4 at 16B-aligned (q*64 + kt*16 + quad*4).
__global__ void wa_prep_kernel(const int* __restrict__ rpi,
                               const float* __restrict__ rpb,
                               const float* __restrict__ qkv_w,
                               const float* __restrict__ proj_w,
                               const float* __restrict__ maskp,
                               float* __restrict__ bias,
                               unsigned short* __restrict__ wqkv,
                               unsigned short* __restrict__ wproj,
                               float* __restrict__ cmb2) {
    __shared__ int is64_s;
    if (threadIdx.x < 64) {
        int z = (rpi[2 * (int)threadIdx.x + 1] == 0) ? 1 : 0;
        unsigned long long b = __ballot(z);
        if (threadIdx.x == 0) is64_s = (__popcll(b) >= 48) ? 1 : 0;
    }
    __syncthreads();
    const int is64 = is64_s;
    const int base3 = BIAS_ELEMS + WQKV_ELEMS + WPROJ_ELEMS;
    const int total = base3 + (cmb2 ? CMB2_ELEMS : 0);
    for (int idx = blockIdx.x * blockDim.x + threadIdx.x; idx < total;
         idx += gridDim.x * blockDim.x) {
        if (idx < BIAS_ELEMS) {
            int h  = idx / (NTOK * NTOK);
            int nm = idx - h * (NTOK * NTOK);
            int r  = is64 ? rpi[2 * nm] : rpi[nm];
            bias[idx] = rpb[r * HEADS + h];
        } else if (idx < BIAS_ELEMS + WQKV_ELEMS) {
            int i = idx - BIAS_ELEMS;
            wqkv[i] = f2bf(qkv_w[i]);
        } else if (idx < base3) {
            int i = idx - BIAS_ELEMS - WQKV_ELEMS;
            wproj[i] = f2bf(proj_w[i]);
        } else {
            int i2  = idx - base3;
            int win = i2 / (HEADS * NTOK * 64);
            int rem = i2 - win * (HEADS * NTOK * 64);
            int h   = rem / (NTOK * 64);
            int rm2 = rem - h * (NTOK * 64);
            int q   = rm2 >> 6;
            int k   = rm2 & 63;
            float v = 0.f;
            if (k < NTOK) {
                int nm = q * NTOK + k;
                int r  = is64 ? rpi[2 * nm] : rpi[nm];
                v = rpb[r * HEADS + h] + maskp[win * (NTOK * NTOK) + nm];
            }
            cmb2[i2] = v;
        }
    }
}

// ---------------- K2: fused QKV + attention + output projection ----------------
// One block per window, 2 blocks/CU (LDS 79904 <= 81920).
//
// REGISTER MODEL (R1-R6): rocprof VGPR_Count EXCLUDES AGPRs; occupancy =
// floor(512/(V+A)) waves/EU; __launch_bounds__ 2nd arg = min waves/EU
// (cap 512/N). Phase 1 stays CHUNKED (Q,V,K: acc[3][2]=24 AGPR) — R6 proved
// near-zero spill. kf snapshot eliminated (K persists in LDS; S is gone).
//
// HEAD LOOP (new): swapped QK^T — mfma(A=K, B=Q) puts a full softmax row
// per lane (q=l16 fixed; k = kt*16+quad*4+rr in-lane + cross-quad). Softmax
// fully in-register (2 shfl_xor); 1/sum folded into P (no sinv); QK scale
// folded into Q at phase-1 epilogue. No S buffer, no 392-thread phase.
// Pipelined: waves 0-3 run 2a'(h) while waves 4-7 run 2c(h-1); P written
// after the mid barrier. 2 barriers/head.
//
// Junk-tolerance (all verified finite): K pad rows 49-63 alias P region
// (bf16 probs / x leftovers); P pad rows 49-63 alias sq start (bf16 Q/O);
// MFMA garbage pollutes only the D-rows/cols fed by the garbage operand
// rows, which are masked (k>=49 -> p=0) or discarded (i>=49 not stored).
template <bool CMB>
__global__ __launch_bounds__(512, 4)
void wa_attn_kernel(const float* __restrict__ x,
                    const float* __restrict__ maskp,
                    const unsigned short* __restrict__ wqkv,
                    const float* __restrict__ qkv_b,
                    const float* __restrict__ biasp,
                    const unsigned short* __restrict__ wproj,
                    const float* __restrict__ proj_b,
                    const float* __restrict__ cmbp,
                    float* __restrict__ out) {
    __shared__ __attribute__((aligned(16))) unsigned short lds[LDS_USHORTS];
    unsigned short* sx     = lds;                          // phase 0/1 staging
    unsigned short* kstage = lds;                          // head loop: K rows
    unsigned short* P      = lds + P_EOFF;                 // head loop: P[64][PS]
    unsigned short* sq     = lds + USP_BYTES / 2;          // Q (scaled) -> O
    unsigned short* sv     = lds + USP_BYTES / 2 + 64 * XS; // V^T

    const int tid  = threadIdx.x;
    const int wave = tid >> 6;
    const int lane = tid & 63;
    const int quad = lane >> 4;
    const int l16  = lane & 15;
    const int bw   = blockIdx.x;
    const int win  = bw & (NWIN - 1);
    const float scale = 0.17677669529663687f;

    // ---- phase 0: stage x window fp32 -> bf16 LDS, zero pad rows 49..63 ----
    {
        const float4* xw = (const float4*)(x + (size_t)bw * (NTOK * DIM));
        for (int idx = tid; idx < NTOK * DIM / 4; idx += 512) {
            int row = idx / 48, c4 = idx - row * 48;
            float4 v = xw[idx];
            unsigned int lo = (unsigned int)f2bf(v.x) | ((unsigned int)f2bf(v.y) << 16);
            unsigned int hi = (unsigned int)f2bf(v.z) | ((unsigned int)f2bf(v.w) << 16);
            *(uint2*)&sx[row * XS + c4 * 4] = make_uint2(lo, hi);
        }
        for (int idx = tid; idx < 15 * 24; idx += 512) {
            int row = 49 + idx / 24, c8 = idx - (idx / 24) * 24;
            *(uint4*)&sx[row * XS + c8 * 8] = make_uint4(0, 0, 0, 0);
        }
    }
    __syncthreads();

    // ---- phase 1: QKV = X * Wqkv^T + b, CHUNKED (Q, V, then K) ----
    // acc[3][2] = 24 AGPR per chunk; static unroll mandatory (scratch demotion).
    {
        const int wm = wave >> 2;
        const int wn = wave & 3;
        #pragma unroll
        for (int cc = 0; cc < 3; ++cc) {
            const int c = (cc == 0) ? 0 : (cc == 1 ? 2 : 1);   // Q, V, K(last)
            f32x4 acc[3][2];
            #pragma unroll
            for (int r = 0; r < 3; ++r)
                #pragma unroll
                for (int mi = 0; mi < 2; ++mi) acc[r][mi] = (f32x4){0.f, 0.f, 0.f, 0.f};
            for (int k0 = 0; k0 < DIM; k0 += 32) {
                short8 af[2];
                #pragma unroll
                for (int mi = 0; mi < 2; ++mi)
                    af[mi] = *(const short8*)&sx[((wm * 2 + mi) * 16 + l16) * XS + k0 + quad * 8];
                #pragma unroll
                for (int r = 0; r < 3; ++r) {
                    int n0 = c * 192 + (wn + 4 * r) * 16;
                    short8 bf = *(const short8*)(wqkv + (n0 + l16) * DIM + k0 + quad * 8);
                    #pragma unroll
                    for (int mi = 0; mi < 2; ++mi)
                        acc[r][mi] = __builtin_amdgcn_mfma_f32_16x16x32_bf16(af[mi], bf, acc[r][mi], 0, 0, 0);
                }
            }
            if (c == 1) __syncthreads();   // all sx reads done before K overwrites it
            #pragma unroll
            for (int r = 0; r < 3; ++r) {
                int ccol = (wn + 4 * r) * 16 + l16;
                float cb = qkv_b[c * 192 + ccol];
                #pragma unroll
                for (int mi = 0; mi < 2; ++mi) {
                    int mbase = (wm * 2 + mi) * 16 + quad * 4;
                    if (c == 2) {
                        // V: 4 rr consecutive tokens -> uint2 (V^T layout)
                        unsigned int lo = (unsigned int)f2bf(acc[r][mi][0] + cb) |
                                          ((unsigned int)f2bf(acc[r][mi][1] + cb) << 16);
                        unsigned int hi = (unsigned int)f2bf(acc[r][mi][2] + cb) |
                                          ((unsigned int)f2bf(acc[r][mi][3] + cb) << 16);
                        *(uint2*)&sv[ccol * VS + mbase] = make_uint2(lo, hi);
                    } else if (c == 1) {
                        // K: pad-row writes (>=49) land in P region pre-head-loop: harmless
                        #pragma unroll
                        for (int rr = 0; rr < 4; ++rr)
                            kstage[(mbase + rr) * XS + ccol] = f2bf(acc[r][mi][rr] + cb);
                    } else {
                        // Q: fold QK scale here (saves 16 mults/lane/head later)
                        #pragma unroll
                        for (int rr = 0; rr < 4; ++rr)
                            sq[(mbase + rr) * XS + ccol] = f2bf((acc[r][mi][rr] + cb) * scale);
                    }
                }
            }
        }
    }
    __syncthreads();

    // ---- head loop: pipelined {2a'(h) on waves 0-3 || 2c(h-1) on waves 4-7} ----
    #pragma unroll
    for (int h = 0; h < HEADS; ++h) {
        unsigned int pw[4][2];
        int qv = 0;
        if (wave < 4) {
            // 2a': S^T = K Q^T (swapped MFMA), in-register softmax, normalized P
            const int qt = wave;
            const int q  = qt * 16 + l16;
            qv = (q < NTOK);
            short8 bq = *(const short8*)&sq[(qt * 16 + l16) * XS + h * 32 + quad * 8];
            f32x4 d[4];
            #pragma unroll
            for (int kt = 0; kt < 4; ++kt) {
                short8 ak = *(const short8*)&kstage[(kt * 16 + l16) * XS + h * 32 + quad * 8];
                d[kt] = __builtin_amdgcn_mfma_f32_16x16x32_bf16(ak, bq, (f32x4){0.f, 0.f, 0.f, 0.f}, 0, 0, 0);
            }
            float s[4][4];
            float m = -1e30f;
            #pragma unroll
            for (int kt = 0; kt < 4; ++kt) {
                int kbase = kt * 16 + quad * 4;
                if (CMB) {
                    const int qc = qv ? q : (NTOK - 1);
                    float4 c4 = *(const float4*)(cmbp + (((size_t)(win * HEADS + h)) * NTOK + qc) * 64 + kbase);
                    const float* c4p = (const float*)&c4;
                    #pragma unroll
                    for (int rr = 0; rr < 4; ++rr) {
                        int k = kbase + rr;
                        s[kt][rr] = (k < NTOK && qv) ? d[kt][rr] + c4p[rr] : -30000.f;
                        m = fmaxf(m, s[kt][rr]);
                    }
                } else {
                    const float* bh = biasp + h * (NTOK * NTOK);
                    const float* mw = maskp + win * (NTOK * NTOK);
                    #pragma unroll
                    for (int rr = 0; rr < 4; ++rr) {
                        int k = kbase + rr;
                        float v = -30000.f;
                        if (k < NTOK && qv) v = d[kt][rr] + bh[q * NTOK + k] + mw[q * NTOK + k];
                        s[kt][rr] = v;
                        m = fmaxf(m, v);
                    }
                }
            }
            m = fmaxf(m, __shfl_xor(m, 16));
            m = fmaxf(m, __shfl_xor(m, 32));
            float p[4][4];
            float sum = 0.f;
            #pragma unroll
            for (int kt = 0; kt < 4; ++kt)
                #pragma unroll
                for (int rr = 0; rr < 4; ++rr) {
                    p[kt][rr] = __expf(s[kt][rr] - m);
                    sum += p[kt][rr];
                }
            sum += __shfl_xor(sum, 16);
            sum += __shfl_xor(sum, 32);
            float si = 1.f / sum;
            #pragma unroll
            for (int kt = 0; kt < 4; ++kt) {
                pw[kt][0] = (unsigned int)f2bf(p[kt][0] * si) | ((unsigned int)f2bf(p[kt][1] * si) << 16);
                pw[kt][1] = (unsigned int)f2bf(p[kt][2] * si) | ((unsigned int)f2bf(p[kt][3] * si) << 16);
            }
        } else if (h > 0) {
            // 2c(h-1): O = P V (P normalized), waves 4-7, mt = wave-4
            const int hp = h - 1, mt = wave - 4;
            #pragma unroll
            for (int nt = 0; nt < 2; ++nt) {
                f32x4 o = {0.f, 0.f, 0.f, 0.f};
                #pragma unroll
                for (int k0 = 0; k0 < 64; k0 += 32) {
                    short8 ap = *(const short8*)&P[(mt * 16 + l16) * PS + k0 + quad * 8];
                    short8 bv = *(const short8*)&sv[(hp * 32 + nt * 16 + l16) * VS + k0 + quad * 8];
                    o = __builtin_amdgcn_mfma_f32_16x16x32_bf16(ap, bv, o, 0, 0, 0);
                }
                #pragma unroll
                for (int rr = 0; rr < 4; ++rr) {
                    int i = mt * 16 + quad * 4 + rr;
                    if (i < NTOK)
                        sq[i * XS + hp * 32 + nt * 16 + l16] = f2bf(o[rr]);
                }
            }
        }
        __syncthreads();   // 2c's P reads done; 2a' compute done
        if (wave < 4 && qv) {
            const int q = wave * 16 + l16;
            #pragma unroll
            for (int kt = 0; kt < 4; ++kt)
                *(uint2*)&P[q * PS + kt * 16 + quad * 4] = make_uint2(pw[kt][0], pw[kt][1]);
        }
        __syncthreads();   // P(h) visible
    }
    // final 2c for head 5: all 8 waves (mt = wave>>1, nt = wave&1)
    {
        const int hp = HEADS - 1, mt = wave >> 1, nt = wave & 1;
        f32x4 o = {0.f, 0.f, 0.f, 0.f};
        #pragma unroll
        for (int k0 = 0; k0 < 64; k0 += 32) {
            short8 ap = *(const short8*)&P[(mt * 16 + l16) * PS + k0 + quad * 8];
            short8 bv = *(const short8*)&sv[(hp * 32 + nt * 16 + l16) * VS + k0 + quad * 8];
            o = __builtin_amdgcn_mfma_f32_16x16x32_bf16(ap, bv, o, 0, 0, 0);
        }
        #pragma unroll
        for (int rr = 0; rr < 4; ++rr) {
            int i = mt * 16 + quad * 4 + rr;
            if (i < NTOK)
                sq[i * XS + hp * 32 + nt * 16 + l16] = f2bf(o[rr]);
        }
    }
    __syncthreads();

    // ---- phase 3: fused output projection  out = O @ proj_w^T + proj_b ----
    // sq pad rows (49-63) hold stale finite bf16 -> garbage D rows, discarded.
    {
        const int mh = wave >> 2;
        const int wv = wave & 3;
        f32x4 pacc[3][2];
        #pragma unroll
        for (int r = 0; r < 3; ++r)
            #pragma unroll
            for (int mi = 0; mi < 2; ++mi) pacc[r][mi] = (f32x4){0.f, 0.f, 0.f, 0.f};
        for (int k0 = 0; k0 < DIM; k0 += 32) {
            short8 af[2];
            #pragma unroll
            for (int mi = 0; mi < 2; ++mi)
                af[mi] = *(const short8*)&sq[((mh * 2 + mi) * 16 + l16) * XS + k0 + quad * 8];
            #pragma unroll
            for (int r = 0; r < 3; ++r) {
                int n0 = (wv + 4 * r) * 16;
                short8 bf = *(const short8*)(wproj + (n0 + l16) * DIM + k0 + quad * 8);
                #pragma unroll
                for (int mi = 0; mi < 2; ++mi)
                    pacc[r][mi] = __builtin_amdgcn_mfma_f32_16x16x32_bf16(af[mi], bf, pacc[r][mi], 0, 0, 0);
            }
        }
        #pragma unroll
        for (int r = 0; r < 3; ++r) {
            int n0 = (wv + 4 * r) * 16;
            float cb = proj_b[n0 + l16];
            #pragma unroll
            for (int mi = 0; mi < 2; ++mi) {
                #pragma unroll
                for (int rr = 0; rr < 4; ++rr) {
                    int m = (mh * 2 + mi) * 16 + quad * 4 + rr;
                    if (m < NTOK)
                        out[((size_t)bw * NTOK + m) * DIM + n0 + l16] = pacc[r][mi][rr] + cb;
                }
            }
        }
    }
}

extern "C" void kernel_launch(void* const* d_in, const int* in_sizes, int n_in,
                              void* d_out, int out_size, void* d_ws, size_t ws_size,
                              hipStream_t stream) {
    const float* x      = (const float*)d_in[0];
    const int*   rpi    = (const int*)d_in[1];
    const float* maskp  = (const float*)d_in[2];
    const float* qkv_w  = (const float*)d_in[3];
    const float* qkv_b  = (const float*)d_in[4];
    const float* proj_w = (const float*)d_in[5];
    const float* proj_b = (const float*)d_in[6];
    const float* rpb    = (const float*)d_in[7];
    float* out = (float*)d_out;

    float* bias = (float*)d_ws;
    unsigned short* wqkv  = (unsigned short*)d_ws + WQKV_SOFF;
    unsigned short* wproj = (unsigned short*)d_ws + WPROJ_SOFF;
    float* cmb2 = nullptr;                       // 4.82 MB padded bias+mask table
    if (ws_size >= CMB_BOFF + (size_t)CMB2_ELEMS * 4)
        cmb2 = (float*)((char*)d_ws + CMB_BOFF);

    wa_prep_kernel<<<640, 256, 0, stream>>>(rpi, rpb, qkv_w, proj_w, maskp,
                                            bias, wqkv, wproj, cmb2);
    if (cmb2)
        wa_attn_kernel<true><<<4096, 512, 0, stream>>>(x, maskp, wqkv, qkv_b, bias,
                                                       wproj, proj_b, cmb2, out);
    else
        wa_attn_kernel<false><<<4096, 512, 0, stream>>>(x, maskp, wqkv, qkv_b, bias,
                                                        wproj, proj_b, nullptr, out);
}